// Round 11
// baseline (243.313 us; speedup 1.0000x reference)
//
#include <hip/hip_runtime.h>

// MHA: D_MODEL=1024, D_K=64, H=16, N=2, T=2048. fp32 I/O, bf16 MFMA internals.
// R21: R20 permlane direction fix. R20 failed absmax=0.23 (moderate: P
// attached to wrong keys). Audit cleared all other layouts; the one 2-way
// ambiguity is v_permlane32_swap_b32 direction. R20 assumed vdst.lo<->vsrc.hi
// (V1); failure implies HW is vdst.row1<->vsrc.row0 (V2):
//   vdst_new = [vdst_lo | vsrc_lo], vsrc_new = [vdst_hi | vsrc_hi].
// B-frag need: word i = [A_lo|B_lo], word 2+i = [A_hi|B_hi] with A=c[2t2]
// (sg=2t2), B=c[2t2+1]. Under V2: swap(vdst=A, vsrc=B) -> word_i = vdst_new,
// word_{2+i} = vsrc_new. Only this flip changed vs R20.
// flash: 32x32 MFMA, P in regs (Ps LDS round-trip + its 3.1M bank conflicts
// eliminated), LDS 24.6KB, 16 cvt_pk + 8 permlane per wave-iter.
// Everything else R18 exact: fused prep, BN=64 gemm_qkv (BN=128 worse twice),
// gemm_out, K dbuf + counted vmcnt (vmcnt(4)/vmcnt(2)), packed mask + fast
// path, exp2 fold (Q pre-scaled 0.125*log2e), ws layout (inputs never
// written).

typedef __bf16 bf16;
typedef __bf16 bf16x8 __attribute__((ext_vector_type(8)));
typedef __bf16 bf16x4 __attribute__((ext_vector_type(4)));
typedef float f32x4 __attribute__((ext_vector_type(4)));
typedef float f32x16 __attribute__((ext_vector_type(16)));
typedef unsigned u32x4 __attribute__((ext_vector_type(4)));

#define MFMA16(a, b, c) __builtin_amdgcn_mfma_f32_16x16x32_bf16((a), (b), (c), 0, 0, 0)
#define MFMA32(a, b, c) __builtin_amdgcn_mfma_f32_32x32x16_bf16((a), (b), (c), 0, 0, 0)
#define EXP2(x) __builtin_amdgcn_exp2f(x)

__device__ __forceinline__ void load_lds16(const bf16* g, bf16* l) {
  __builtin_amdgcn_global_load_lds(
      (const __attribute__((address_space(1))) unsigned int*)g,
      (__attribute__((address_space(3))) unsigned int*)l, 16, 0, 0);
}

__device__ __forceinline__ bf16x8 cvt8(const float* __restrict__ p) {
  const f32x4 a = *(const f32x4*)p;
  const f32x4 b = *(const f32x4*)(p + 4);
  bf16x8 r;
  r[0] = (bf16)a[0]; r[1] = (bf16)a[1]; r[2] = (bf16)a[2]; r[3] = (bf16)a[3];
  r[4] = (bf16)b[0]; r[5] = (bf16)b[1]; r[6] = (bf16)b[2]; r[7] = (bf16)b[3];
  return r;
}

// ---------------------------------------------------------------------------
// prep: fused prepass (R18 exact). Blocks [0,6144): k,q,v fp32 -> bf16.
// Blocks [6144,7168): W transpose + maskpack (mbits in d_out head).
// ---------------------------------------------------------------------------
__global__ __launch_bounds__(256) void prep(
    const float* __restrict__ ka, const float* __restrict__ qa,
    const float* __restrict__ va, bf16* __restrict__ kb,
    bf16* __restrict__ qb, bf16* __restrict__ vb,
    const float* __restrict__ W0, const float* __restrict__ W1,
    const float* __restrict__ W2, const float* __restrict__ W3,
    bf16* __restrict__ T0, bf16* __restrict__ T1, bf16* __restrict__ T2,
    bf16* __restrict__ T3, const int* __restrict__ mask,
    unsigned long long* __restrict__ mbits) {
  __shared__ bf16 t[64 * 72];
  const int tid = threadIdx.x;
  if (blockIdx.x < 6144) {
    const size_t i = ((size_t)blockIdx.x * 256 + tid) * 8;
    const int which = (int)(i >> 22);
    const size_t off = i & ((size_t)(1u << 22) - 1);
    const float* src = which == 0 ? ka : (which == 1 ? qa : va);
    bf16* dst = which == 0 ? kb : (which == 1 ? qb : vb);
    *(bf16x8*)&dst[off] = cvt8(&src[off]);
    return;
  }
  const int tb = blockIdx.x - 6144;
  const int z = tb >> 8;
  const int rem = tb & 255;
  const int by = rem >> 4, bx = rem & 15;
  const float* W = z == 0 ? W0 : (z == 1 ? W1 : (z == 2 ? W2 : W3));
  bf16* T = z == 0 ? T0 : (z == 1 ? T1 : (z == 2 ? T2 : T3));
  const int kBase = by * 64, nBase = bx * 64;
  const int row = tid >> 2, cs = (tid & 3) * 16;

  const float* src = &W[(size_t)(kBase + row) * 1024 + nBase + cs];
  *(bf16x8*)&t[row * 72 + cs] = cvt8(src);
  *(bf16x8*)&t[row * 72 + cs + 8] = cvt8(src + 8);
  __syncthreads();

  const int n = tid >> 2, ks = (tid & 3) * 16;
  bf16 buf[16];
#pragma unroll
  for (int j = 0; j < 16; ++j) buf[j] = t[(ks + j) * 72 + n];
  bf16* dst = &T[(size_t)(nBase + n) * 1024 + kBase + ks];
  *(bf16x8*)&dst[0] = *(bf16x8*)&buf[0];
  *(bf16x8*)&dst[8] = *(bf16x8*)&buf[8];

  if (bx == 0 && by == 0 && tid < 128) {
    const int w = tid >> 6, lane = tid & 63;
#pragma unroll
    for (int i = 0; i < 8; ++i) {
      const int tile = z * 16 + w * 8 + i;
      const unsigned long long bits = __ballot(mask[tile * 64 + lane] != 0);
      if (lane == 0) mbits[tile] = bits;
    }
  }
}

// ---------------------------------------------------------------------------
// gemm_qkv (R14/R18 exact, BN=64): fused K/V/Q projections. BM=128, BN=64,
// BK=64; 4 waves, 64x32 wave tile; 24KB LDS -> 6 blocks/CU; grid (16,32,3).
// z=0: K (bh,t,d). z=1: Vt (bh,d,t) via LDS transpose. z=2: Q, *0.125*log2e.
// ---------------------------------------------------------------------------
__global__ __launch_bounds__(256) void gemm_qkv(
    const bf16* __restrict__ kb, const bf16* __restrict__ vb,
    const bf16* __restrict__ qb, const bf16* __restrict__ WkT,
    const bf16* __restrict__ WvT, const bf16* __restrict__ WqT,
    const float* __restrict__ bk, const float* __restrict__ bv,
    const float* __restrict__ bq, bf16* __restrict__ K_buf,
    bf16* __restrict__ Vt_buf, bf16* __restrict__ Q_buf) {
  __shared__ __align__(16) bf16 S[12288];
  bf16* As = S;
  bf16* Ws = S + 8192;
  const int tid = threadIdx.x;
  const int lane = tid & 63, w = tid >> 6;
  const int l15 = lane & 15, quad = lane >> 4;
  const int z = blockIdx.z;
  const bf16* X = z == 0 ? kb : (z == 1 ? vb : qb);
  const bf16* WT = z == 0 ? WkT : (z == 1 ? WvT : WqT);
  const float* B = z == 0 ? bk : (z == 1 ? bv : bq);
  const int mBase = blockIdx.y * 128, nBase = blockIdx.x * 64;
  const int wm = (w >> 1) * 64, wn = (w & 1) * 32;

  const int r8 = tid >> 3;
  const int jg = ((tid & 7) ^ (r8 & 7)) * 8;
  const int sw = l15 & 7;

  f32x4 acc[4][2] = {};

  for (int k0 = 0; k0 < 1024; k0 += 64) {
    __syncthreads();
#pragma unroll
    for (int i = 0; i < 4; ++i)
      load_lds16(&X[(size_t)(mBase + r8 + i * 32) * 1024 + k0 + jg],
                 &As[(tid + i * 256) * 8]);
#pragma unroll
    for (int i = 0; i < 2; ++i)
      load_lds16(&WT[(size_t)(nBase + r8 + i * 32) * 1024 + k0 + jg],
                 &Ws[(tid + i * 256) * 8]);
    __syncthreads();

#pragma unroll
    for (int k2 = 0; k2 < 2; ++k2) {
      const int col = ((k2 * 4 + quad) ^ sw) * 8;
      bf16x8 a[4], bb[2];
#pragma unroll
      for (int mt = 0; mt < 4; ++mt)
        a[mt] = *(const bf16x8*)&As[(wm + mt * 16 + l15) * 64 + col];
#pragma unroll
      for (int nt = 0; nt < 2; ++nt)
        bb[nt] = *(const bf16x8*)&Ws[(wn + nt * 16 + l15) * 64 + col];
#pragma unroll
      for (int mt = 0; mt < 4; ++mt)
#pragma unroll
        for (int nt = 0; nt < 2; ++nt)
          acc[mt][nt] = MFMA16(a[mt], bb[nt], acc[mt][nt]);
    }
  }

  const int h = nBase >> 6;
  if (z != 1) {
    // 0.125 * log2(e): flash uses exp2(s) == e^(q.k/8)
    const float scale = (z == 2) ? 0.18033688011112042f : 1.0f;
    bf16* o = (z == 0) ? K_buf : Q_buf;
#pragma unroll
    for (int nt = 0; nt < 2; ++nt) {
      const int n = nBase + wn + nt * 16 + l15;
      const float bias = B[n];
      const int d = n & 63;
#pragma unroll
      for (int mt = 0; mt < 4; ++mt)
#pragma unroll
        for (int r = 0; r < 4; ++r) {
          const int m = mBase + wm + mt * 16 + quad * 4 + r;
          const int b = m >> 11, t = m & 2047;
          o[((size_t)(b * 16 + h) * 2048 + t) * 64 + d] =
              (bf16)((acc[mt][nt][r] + bias) * scale);
        }
    }
  } else {
    __syncthreads();
    bf16* Tb = &S[w * 2304];  // 32 x 72
#pragma unroll
    for (int nt = 0; nt < 2; ++nt) {
      const int n = nBase + wn + nt * 16 + l15;
      const float bias = B[n];
#pragma unroll
      for (int mt = 0; mt < 4; ++mt) {
        bf16x4 pk;
#pragma unroll
        for (int r = 0; r < 4; ++r) pk[r] = (bf16)(acc[mt][nt][r] + bias);
        *(bf16x4*)&Tb[(nt * 16 + l15) * 72 + mt * 16 + quad * 4] = pk;
      }
    }
    const int b = mBase >> 11;
#pragma unroll
    for (int i = 0; i < 4; ++i) {
      const int dl = i * 8 + (lane >> 3), ts = (lane & 7) * 8;
      const bf16x8 vv = *(const bf16x8*)&Tb[dl * 72 + ts];
      const int d = wn + dl;
      const int t = (mBase + wm + ts) & 2047;
      *(bf16x8*)&Vt_buf[((size_t)(b * 16 + h) * 64 + d) * 2048 + t] = vv;
    }
  }
}

// ---------------------------------------------------------------------------
// gemm_out (R9 exact): out = A @ WoT^T + bo -> fp32. BM=128, BN=64, BK=64.
// ---------------------------------------------------------------------------
__global__ __launch_bounds__(256) void gemm_out(const bf16* __restrict__ X,
                                                const bf16* __restrict__ WT,
                                                const float* __restrict__ B,
                                                float* __restrict__ out) {
  __shared__ __align__(16) bf16 As[128 * 64];
  __shared__ __align__(16) bf16 Ws[64 * 64];
  const int tid = threadIdx.x;
  const int lane = tid & 63, w = tid >> 6;
  const int l15 = lane & 15, quad = lane >> 4;
  const int mBase = blockIdx.y * 128, nBase = blockIdx.x * 64;
  const int wm = (w >> 1) * 64, wn = (w & 1) * 32;

  const int r8 = tid >> 3;
  const int jg = ((tid & 7) ^ (r8 & 7)) * 8;
  const int sw = l15 & 7;

  f32x4 acc[4][2] = {};

  for (int k0 = 0; k0 < 1024; k0 += 64) {
    __syncthreads();
#pragma unroll
    for (int i = 0; i < 4; ++i)
      load_lds16(&X[(size_t)(mBase + r8 + i * 32) * 1024 + k0 + jg],
                 &As[(tid + i * 256) * 8]);
#pragma unroll
    for (int i = 0; i < 2; ++i)
      load_lds16(&WT[(size_t)(nBase + r8 + i * 32) * 1024 + k0 + jg],
                 &Ws[(tid + i * 256) * 8]);
    __syncthreads();

#pragma unroll
    for (int k2 = 0; k2 < 2; ++k2) {
      const int col = ((k2 * 4 + quad) ^ sw) * 8;
      bf16x8 a[4], bb[2];
#pragma unroll
      for (int mt = 0; mt < 4; ++mt)
        a[mt] = *(const bf16x8*)&As[(wm + mt * 16 + l15) * 64 + col];
#pragma unroll
      for (int nt = 0; nt < 2; ++nt)
        bb[nt] = *(const bf16x8*)&Ws[(wn + nt * 16 + l15) * 64 + col];
#pragma unroll
      for (int mt = 0; mt < 4; ++mt)
#pragma unroll
        for (int nt = 0; nt < 2; ++nt)
          acc[mt][nt] = MFMA16(a[mt], bb[nt], acc[mt][nt]);
    }
  }

#pragma unroll
  for (int nt = 0; nt < 2; ++nt) {
    const int n = nBase + wn + nt * 16 + l15;
    const float bias = B[n];
#pragma unroll
    for (int mt = 0; mt < 4; ++mt)
#pragma unroll
      for (int r = 0; r < 4; ++r) {
        const int m = mBase + wm + mt * 16 + quad * 4 + r;
        out[(size_t)m * 1024 + n] = acc[mt][nt][r] + bias;
      }
  }
}

// ---------------------------------------------------------------------------
// flash_attn (R21): 32x32 MFMA, in-register P. 128 q/block (4 waves x 32 q),
// grid (16,32) = 512. QK^T: 2 kk x 4 kd = 8 MFMA (S^T: q=lane&31,
// key=(reg&3)+8(reg>>2)+4hi); softmax+cvt_pk in regs; permlane32_swap (V2:
// vdst_new=[vdst_lo|vsrc_lo], vsrc_new=[vdst_hi|vsrc_hi]) builds PV B-frags:
// swap(vdst=A=c[2t2], vsrc=B=c[2t2+1]) -> word_i=vdst_new, word_{2+i}=
// vsrc_new. PV: 2 dt x 4 seg = 8 MFMA. K dbuf + counted vmcnt (R14):
// vmcnt(4)/vmcnt(2). LDS 24.6KB (Ps eliminated).
// ---------------------------------------------------------------------------
__global__ __launch_bounds__(256) void flash_attn(
    const bf16* __restrict__ Q, const bf16* __restrict__ K,
    const bf16* __restrict__ Vt, const unsigned long long* __restrict__ mbits,
    bf16* __restrict__ A) {
  __shared__ __align__(16) bf16 Ks[2][64 * 64];  // [key][d] swizzled, dbuf 16KB
  __shared__ __align__(16) bf16 Vs[64 * 64];     // [d][key] swizzled 8KB

  const int tid = threadIdx.x;
  const int lane = tid & 63, w = tid >> 6;
  const int l31 = lane & 31, hi = lane >> 5;
  const int m7 = l31 & 7;
  const int bh = blockIdx.y;
  const int b = bh >> 4, h = bh & 15;
  const int qt = blockIdx.x * 128;

  const int r8 = tid >> 3;
  const int jg = ((tid & 7) ^ (r8 & 7)) * 8;

  // Q B-frags: col=q=lane&31, k-elem d = 16t + 8*hi + j.
  const int q = qt + w * 32 + l31;
  const size_t qbase = ((size_t)bh * 2048 + q) * 64;
  bf16x8 qf[4];
#pragma unroll
  for (int t = 0; t < 4; ++t)
    qf[t] = *(const bf16x8*)&Q[qbase + t * 16 + hi * 8];

  f32x16 o_acc[2] = {};  // O^T: d = (reg&3)+8(reg>>2)+4hi + 32dt, q = lane&31
  float rs = 0.0f;

  // Prologue: K(0) -> Ks[0]. Outstanding: 2 (matches steady state).
#pragma unroll
  for (int i = 0; i < 2; ++i)
    load_lds16(&K[((size_t)bh * 2048 + r8 + i * 32) * 64 + jg],
               &Ks[0][(tid + i * 256) * 8]);

  int cur = 0;
  for (int kt = 0; kt < 2048; kt += 64) {
    // barrier[1]: PV(t-1) done -> Vs free; QK(t-1) done -> Ks[cur^1] free.
    __builtin_amdgcn_s_barrier();

    const unsigned long long mb = mbits[b * 32 + (kt >> 6)];

    // Issue V(t) -> Vs (vmcnt +2)
#pragma unroll
    for (int i = 0; i < 2; ++i)
      load_lds16(&Vt[((size_t)bh * 64 + r8 + i * 32) * 2048 + kt + jg],
                 &Vs[(tid + i * 256) * 8]);
    // Issue K(t+1) -> Ks[cur^1] (vmcnt +2); last iter wraps into dead buffer.
    const int ktn = (kt + 64) & 2047;
#pragma unroll
    for (int i = 0; i < 2; ++i)
      load_lds16(&K[((size_t)bh * 2048 + ktn + r8 + i * 32) * 64 + jg],
                 &Ks[cur ^ 1][(tid + i * 256) * 8]);

    // K(t) arrived (4 newer ops outstanding); make it visible block-wide.
    asm volatile("s_waitcnt vmcnt(4)" ::: "memory");
    __builtin_amdgcn_s_barrier();  // barrier[2]

    // QK^T: S^T[key][q], 2 kk-tiles of 32 keys. A=K frag (row=key, k=d),
    // B=Q frag. 8 b128 reads, 8 MFMA.
    const bf16* Kc = Ks[cur];
    f32x16 s_acc[2];
    __builtin_amdgcn_s_setprio(1);
#pragma unroll
    for (int kk = 0; kk < 2; ++kk) {
      f32x16 s = {};
#pragma unroll
      for (int t = 0; t < 4; ++t) {
        const int row = kk * 32 + l31;
        const bf16x8 ak =
            *(const bf16x8*)&Kc[row * 64 + (((2 * t + hi) ^ m7) * 8)];
        s = MFMA32(ak, qf[t], s);
      }
      s_acc[kk] = s;
    }
    __builtin_amdgcn_s_setprio(0);

    // V(t) arrived; K(t+1) stays in flight across the next barrier.
    asm volatile("s_waitcnt vmcnt(2)" ::: "memory");

    // In-register softmax: p = exp2(s) (Q carries 0.125*log2e), pack pairs
    // c[kk][sg][i] = cvt_pk(p[sg*4+2i], p[sg*4+2i+1]) covering keys
    // kk*32 + 8sg + 4hi + 2i + {0,1}.
    unsigned c[2][4][2];
    if (mb + 1ull == 0ull) {
#pragma unroll
      for (int kk = 0; kk < 2; ++kk)
#pragma unroll
        for (int sg = 0; sg < 4; ++sg)
#pragma unroll
          for (int i = 0; i < 2; ++i) {
            const float p0 = EXP2(s_acc[kk][sg * 4 + 2 * i]);
            const float p1 = EXP2(s_acc[kk][sg * 4 + 2 * i + 1]);
            rs += p0 + p1;
            unsigned u;
            asm("v_cvt_pk_bf16_f32 %0, %1, %2" : "=v"(u) : "v"(p0), "v"(p1));
            c[kk][sg][i] = u;
          }
    } else {
#pragma unroll
      for (int kk = 0; kk < 2; ++kk) {
        const unsigned g = (unsigned)(mb >> (kk * 32));
#pragma unroll
        for (int sg = 0; sg < 4; ++sg)
#pragma unroll
          for (int i = 0; i < 2; ++i) {
            const int kl = sg * 8 + hi * 4 + 2 * i;  // key bit within 32
            const float p0 = ((g >> kl) & 1u) ? EXP2(s_acc[kk][sg * 4 + 2 * i]) : 0.0f;
            const float p1 = ((g >> (kl + 1)) & 1u) ? EXP2(s_acc[kk][sg * 4 + 2 * i + 1]) : 0.0f;
            rs += p0 + p1;
            unsigned u;
            asm("v_cvt_pk_bf16_f32 %0, %1, %2" : "=v"(u) : "v"(p0), "v"(p1));
            c[kk][sg][i] = u;
          }
      }
    }

    __builtin_amdgcn_s_barrier();  // barrier[3]: all waves' V(t) -> Vs visible

    // PV: per 16-key segment seg = kk*2+t2, B-frag via 2 permlane32_swap.
    // V2 semantics: swap(vdst=A=c[kk][2t2][i], vsrc=B=c[kk][2t2+1][i]) ->
    //   vdst_new = [A_lo|B_lo] = word i, vsrc_new = [A_hi|B_hi] = word 2+i.
    // Then 2 dt MFMAs with V A-frag (row = d, k-elem = key = 16seg+8hi+j).
    const bf16* Vc = Vs;
    __builtin_amdgcn_s_setprio(1);
#pragma unroll
    for (int kk = 0; kk < 2; ++kk)
#pragma unroll
      for (int t2 = 0; t2 < 2; ++t2) {
        unsigned a0 = c[kk][2 * t2][0], b0 = c[kk][2 * t2 + 1][0];
        asm("v_permlane32_swap_b32 %0, %1" : "+v"(a0), "+v"(b0));
        unsigned a1 = c[kk][2 * t2][1], b1 = c[kk][2 * t2 + 1][1];
        asm("v_permlane32_swap_b32 %0, %1" : "+v"(a1), "+v"(b1));
        u32x4 wv;
        wv[0] = a0; wv[1] = a1; wv[2] = b0; wv[3] = b1;
        const bf16x8 bp = __builtin_bit_cast(bf16x8, wv);
        const int seg = kk * 2 + t2;
#pragma unroll
        for (int dt = 0; dt < 2; ++dt) {
          const int row = dt * 32 + l31;
          const bf16x8 av =
              *(const bf16x8*)&Vc[row * 64 + (((seg * 2 + hi) ^ m7) * 8)];
          o_acc[dt] = MFMA32(av, bp, o_acc[dt]);
        }
      }
    __builtin_amdgcn_s_setprio(0);

    cur ^= 1;
  }

  // Row sum: lanes l and l+32 hold complementary key-halves for the same q.
  rs += __shfl_xor(rs, 32);
  const float inv = rs > 0.0f ? 1.0f / rs : 0.0f;

  // O^T write: d = 32dt + 8rg + 4hi + r, q = lane&31.
  const size_t base = ((size_t)b * 2048 + q) * 1024 + h * 64;
#pragma unroll
  for (int dt = 0; dt < 2; ++dt)
#pragma unroll
    for (int rg = 0; rg < 4; ++rg) {
      bf16x4 ov;
#pragma unroll
      for (int r = 0; r < 4; ++r) ov[r] = (bf16)(o_acc[dt][rg * 4 + r] * inv);
      *(bf16x4*)&A[base + dt * 32 + rg * 8 + hi * 4] = ov;
    }
}

// ---------------------------------------------------------------------------
extern "C" void kernel_launch(void* const* d_in, const int* in_sizes, int n_in,
                              void* d_out, int out_size, void* d_ws, size_t ws_size,
                              hipStream_t stream) {
  const float* k = (const float*)d_in[0];
  const float* q = (const float*)d_in[1];
  const float* v = (const float*)d_in[2];
  const int* mask = (const int*)d_in[3];
  const float* Wk = (const float*)d_in[4];
  const float* bk = (const float*)d_in[5];
  const float* Wq = (const float*)d_in[6];
  const float* bq = (const float*)d_in[7];
  const float* Wv = (const float*)d_in[8];
  const float* bv = (const float*)d_in[9];
  const float* Wo = (const float*)d_in[10];
  const float* bo = (const float*)d_in[11];

  const size_t ELEMS = (size_t)4 * 1024 * 1024;
  const size_t WELEMS = (size_t)1024 * 1024;

  // Fixed ws head: kqv bf16 (24MB) + 4 transposed weights (8MB).
  bf16* kb = (bf16*)d_ws;
  bf16* qb = kb + ELEMS;
  bf16* vb = qb + ELEMS;
  bf16* WkT = vb + ELEMS;
  bf16* WqT = WkT + WELEMS;
  bf16* WvT = WqT + WELEMS;
  bf16* WoT = WvT + WELEMS;

  bf16 *K_buf, *Q_buf, *Vt_buf, *A_buf;
  if (ws_size >= ((size_t)56 << 20)) {
    // Clean layout: intermediates live in ws; inputs never written.
    bf16* ext = WoT + WELEMS;  // ws + 32MB
    K_buf = ext;               // 8MB
    Q_buf = ext + ELEMS;       // 8MB
    Vt_buf = ext + 2 * ELEMS;  // 8MB
    A_buf = kb;                // kb dead after gemm_qkv; flash writes A here
  } else {
    // Fallback (R17 exact): scratch in dead fp32 input buffers.
    K_buf = (bf16*)d_in[0];
    Q_buf = (bf16*)d_in[0] + ELEMS;
    Vt_buf = (bf16*)d_in[2];
    A_buf = (bf16*)d_in[2] + ELEMS;
  }
  // mbits (512B) parked at the head of d_out: written by prep, read by
  // flash_attn, overwritten by gemm_out afterwards (stream-ordered).
  unsigned long long* mbits = (unsigned long long*)d_out;

  prep<<<7168, 256, 0, stream>>>(k, q, v, kb, qb, vb,
                                 Wk, Wq, Wv, Wo, WkT, WqT, WvT, WoT,
                                 mask, mbits);
  gemm_qkv<<<dim3(16, 32, 3), 256, 0, stream>>>(kb, vb, qb, WkT, WvT, WqT,
                                                bk, bv, bq, K_buf, Vt_buf, Q_buf);
  flash_attn<<<dim3(16, 32), 256, 0, stream>>>(Q_buf, K_buf, Vt_buf, mbits, A_buf);
  gemm_out<<<dim3(16, 32), 256, 0, stream>>>(A_buf, WoT, bo, (float*)d_out);
}